// Round 1
// baseline (297.990 us; speedup 1.0000x reference)
//
#include <hip/hip_runtime.h>
#include <cfloat>

#define MEMN 8192
#define FEATD 512
#define BATCH 16

static constexpr float TAU_NEW_C = 0.85f;
static constexpr float D_MIN_C  = 1.5f;
static constexpr float ALPHA_C  = 0.5f;
static constexpr float EPS_C    = 1e-8f;

struct BlockPart { float v; int i; };

// Small mutable state in workspace: scalar state + modified-row side tables.
// At most 16 steps -> at most 16 modified feat/pos rows and 32 recorded edges.
struct State {
  int n, p, ec, mc;
  int edges[64][2];
  int mod_idx[16];
  float mod_pos[16][3];
  float mod_feat[16][FEATD];
};

__global__ void init_state_k(State* st, const int* num_nodes, const int* ptr_in) {
  st->n = *num_nodes;
  st->p = *ptr_in;
  st->ec = 0;
  st->mc = 0;
}

// Kernel A: fused per-row dot(feat[row], h) + ||feat[row]||, scaled score
// v = dot / max(norm, eps)  (positive-constant scaling by ||h|| preserved for argmax),
// block-level argmax partials (tie -> lowest row index).
__global__ __launch_bounds__(256) void sim_argmax_k(
    const float* __restrict__ h_t, const float* __restrict__ feat,
    const State* __restrict__ st, BlockPart* __restrict__ parts, int step) {
  const float* __restrict__ h = h_t + step * FEATD;
  __shared__ int s_mod[16];
  __shared__ int s_n;
  if (threadIdx.x == 0) s_n = st->n;
  if (threadIdx.x < 16) s_mod[threadIdx.x] = (threadIdx.x < st->mc) ? st->mod_idx[threadIdx.x] : -1;
  __syncthreads();
  const int n = s_n;
  const int wave = threadIdx.x >> 6;
  const int lane = threadIdx.x & 63;
  const float4* hv = (const float4*)h;
  const float4 b0 = hv[lane * 2 + 0];
  const float4 b1 = hv[lane * 2 + 1];
  float best = -FLT_MAX; int bidx = 0x7fffffff;
  for (int it = 0; it < MEMN / 1024; ++it) {
    const int row = it * 1024 + (int)blockIdx.x * 4 + wave;
    if (row >= n) continue;
    const float* src = feat + (size_t)row * FEATD;
    #pragma unroll
    for (int k = 0; k < 16; ++k)
      if (s_mod[k] == row) src = st->mod_feat[k];
    const float4* fr = (const float4*)src;
    const float4 a0 = fr[lane * 2 + 0];
    const float4 a1 = fr[lane * 2 + 1];
    float dot = a0.x * b0.x + a0.y * b0.y + a0.z * b0.z + a0.w * b0.w
              + a1.x * b1.x + a1.y * b1.y + a1.z * b1.z + a1.w * b1.w;
    float sq  = a0.x * a0.x + a0.y * a0.y + a0.z * a0.z + a0.w * a0.w
              + a1.x * a1.x + a1.y * a1.y + a1.z * a1.z + a1.w * a1.w;
    #pragma unroll
    for (int off = 32; off; off >>= 1) {
      dot += __shfl_down(dot, off);
      sq  += __shfl_down(sq, off);
    }
    if (lane == 0) {
      const float v = dot / fmaxf(sqrtf(sq), EPS_C);
      if (v > best) { best = v; bidx = row; }  // rows increase with it: strict > keeps first max
    }
  }
  __shared__ float sv[4]; __shared__ int si[4];
  if (lane == 0) { sv[wave] = best; si[wave] = bidx; }
  __syncthreads();
  if (threadIdx.x == 0) {
    float bv = sv[0]; int bi = si[0];
    #pragma unroll
    for (int w = 1; w < 4; ++w)
      if (sv[w] > bv || (sv[w] == bv && si[w] < bi)) { bv = sv[w]; bi = si[w]; }
    parts[blockIdx.x].v = bv;
    parts[blockIdx.x].i = bi;
  }
}

// Kernel B (single block): final argmax, ||h||, decision logic, row write into
// side table, edge recording, adjacency-row sum + recorded-edge delta, output.
__global__ __launch_bounds__(256) void step_update_k(
    const float* __restrict__ h_t, const float* __restrict__ posin,
    const unsigned char* __restrict__ dones, const int* __restrict__ lastv,
    const float* __restrict__ feat, const float* __restrict__ posns,
    const float* __restrict__ adj, State* st, const BlockPart* __restrict__ parts,
    float* __restrict__ out, int step) {
  const int tid = threadIdx.x;
  __shared__ float rv[256]; __shared__ int ri[256];
  __shared__ float red[256];
  rv[tid] = parts[tid].v; ri[tid] = parts[tid].i;
  const float* h = h_t + step * FEATD;
  float sq = 0.f;
  for (int k = tid; k < FEATD; k += 256) { const float x = h[k]; sq += x * x; }
  red[tid] = sq;
  __syncthreads();
  for (int s = 128; s; s >>= 1) {
    if (tid < s) {
      if (rv[tid + s] > rv[tid] || (rv[tid + s] == rv[tid] && ri[tid + s] < ri[tid])) {
        rv[tid] = rv[tid + s]; ri[tid] = ri[tid + s];
      }
      red[tid] += red[tid + s];
    }
    __syncthreads();
  }
  __shared__ int s_done, s_ema, s_widx, s_src, s_dst;
  if (tid == 0) {
    const int n = st->n, p = st->p;
    const float hn = sqrtf(red[0]);
    int best; float max_sim;
    if (ri[0] == 0x7fffffff) { best = 0; max_sim = -2.0f; }
    else { best = ri[0]; max_sim = rv[0] / fmaxf(hn, EPS_C); }
    const float* pb = posns + (size_t)best * 3;
    for (int k = 0; k < st->mc; ++k)
      if (st->mod_idx[k] == best) pb = st->mod_pos[k];
    const float dx = posin[step * 3 + 0] - pb[0];
    const float dy = posin[step * 3 + 1] - pb[1];
    const float dz = posin[step * 3 + 2] - pb[2];
    const float dist = sqrtf(dx * dx + dy * dy + dz * dz);
    const int done = dones[step] ? 1 : 0;
    const bool empty = (n < 1);
    const bool should_add = (max_sim < TAU_NEW_C) || (dist > D_MIN_C);
    const bool has_room = (n < MEMN);
    const int widx = empty ? 0 : (should_add ? (has_room ? n : p) : best);
    const bool ema = (!empty) && (!should_add);
    s_done = done; s_widx = widx; s_ema = ema ? 1 : 0;
    int srcs = -1;
    for (int k = 0; k < st->mc; ++k)
      if (st->mod_idx[k] == widx) srcs = k;
    int dsts = srcs;
    if (!done) {
      if (srcs < 0) { dsts = st->mc; st->mod_idx[dsts] = widx; st->mc = dsts + 1; }
      if (empty || (should_add && has_room)) st->n = n + 1;
      if ((!empty) && should_add && (!has_room)) st->p = (p + 1) % MEMN;
      const int last = lastv[step];
      if (last != -1 && last != widx) {
        const int lc = min(max(last, 0), MEMN - 1);
        const int ec = st->ec;
        st->edges[ec][0] = lc;   st->edges[ec][1] = widx;
        st->edges[ec + 1][0] = widx; st->edges[ec + 1][1] = lc;
        st->ec = ec + 2;
      }
    }
    s_src = srcs; s_dst = dsts;
  }
  __syncthreads();
  if (!s_done) {
    const int widx = s_widx;
    float* dstf = st->mod_feat[s_dst];
    const float* srcf = (s_src >= 0) ? st->mod_feat[s_src] : feat + (size_t)widx * FEATD;
    if (s_ema) {
      for (int k = tid; k < FEATD; k += 256)
        dstf[k] = ALPHA_C * srcf[k] + (1.f - ALPHA_C) * h[k];
    } else {
      for (int k = tid; k < FEATD; k += 256)
        dstf[k] = h[k];
    }
    if (tid < 3) {
      const float* srcp = (s_src >= 0) ? st->mod_pos[s_src] : posns + (size_t)widx * 3;
      st->mod_pos[s_dst][tid] = s_ema ? (ALPHA_C * srcp[tid] + (1.f - ALPHA_C) * posin[step * 3 + tid])
                                      : posin[step * 3 + tid];
    }
  }
  __syncthreads();
  if (s_done) { if (tid == 0) out[step] = 0.f; return; }
  const int cur = s_widx;
  const float* row = adj + (size_t)cur * MEMN;
  float sum = 0.f;
  for (int k = tid; k < MEMN; k += 256) sum += row[k];
  red[tid] = sum;
  __syncthreads();
  for (int s = 128; s; s >>= 1) { if (tid < s) red[tid] += red[tid + s]; __syncthreads(); }
  if (tid == 0) {
    float tot = red[0];
    const int ec = st->ec;
    for (int e = 0; e < ec; ++e) {
      if (st->edges[e][0] == cur) {
        const int c = st->edges[e][1];
        bool dup = false;
        for (int e2 = 0; e2 < e; ++e2)
          if (st->edges[e2][0] == cur && st->edges[e2][1] == c) { dup = true; break; }
        if (!dup && row[c] == 0.f) tot += 1.f;
      }
    }
    out[step] = tot;
  }
}

extern "C" void kernel_launch(void* const* d_in, const int* in_sizes, int n_in,
                              void* d_out, int out_size, void* d_ws, size_t ws_size,
                              hipStream_t stream) {
  const float*         h_t       = (const float*)d_in[0];         // [16,512]
  const float*         cur_pos   = (const float*)d_in[1];         // [16,3]
  const unsigned char* dones     = (const unsigned char*)d_in[2]; // [16] bool (all false here)
  const float*         node_feat = (const float*)d_in[3];         // [8192,512]
  const float*         node_pos  = (const float*)d_in[4];         // [8192,3]
  const float*         adj       = (const float*)d_in[5];         // [8192,8192]
  const int*           num_nodes = (const int*)d_in[6];           // scalar
  const int*           ptr_in    = (const int*)d_in[7];           // scalar
  const int*           lastv     = (const int*)d_in[8];           // [16]
  float* out = (float*)d_out;

  char* ws = (char*)d_ws;
  State* st = (State*)ws;                       // ~33.6 KB
  BlockPart* parts = (BlockPart*)(ws + 36864);  // 256 * 8 B

  init_state_k<<<1, 1, 0, stream>>>(st, num_nodes, ptr_in);
  for (int i = 0; i < BATCH; ++i) {
    sim_argmax_k<<<256, 256, 0, stream>>>(h_t, node_feat, st, parts, i);
    step_update_k<<<1, 256, 0, stream>>>(h_t, cur_pos, dones, lastv, node_feat,
                                         node_pos, adj, st, parts, out, i);
  }
}

// Round 2
// 222.411 us; speedup vs baseline: 1.3398x; 1.3398x over previous
//
#include <hip/hip_runtime.h>
#include <cfloat>

#define MEMN 8192
#define FEATD 512
#define BATCH 16

static constexpr float TAU_NEW_C = 0.85f;
static constexpr float D_MIN_C  = 1.5f;
static constexpr float ALPHA_C  = 0.5f;
static constexpr float EPS_C    = 1e-8f;

// ws layout:
//   S   : float[16][8192]  at +0        (512 KB)  precomputed scores dot/max(|row|,eps)
//   pre : float[16]        at +512KB    speculative adj rowsums for rows [n0, n0+16)
//   hn  : float[16]        after pre    ||h_i||

// Kernel 1: all 16 dots per row in one pass over active rows.
__global__ __launch_bounds__(256) void score_k(
    const float* __restrict__ h_t, const float* __restrict__ feat,
    const int* __restrict__ num_nodes, float* __restrict__ S) {
  __shared__ float sh[BATCH * FEATD];  // 32 KB: all 16 h vectors
  for (int k = threadIdx.x; k < BATCH * FEATD; k += 256) sh[k] = h_t[k];
  __syncthreads();
  const int n0 = *num_nodes;
  const int wave = threadIdx.x >> 6, lane = threadIdx.x & 63;
  const int base = lane * 8;
  for (int j = 0; j < 8; ++j) {
    const int row = (int)blockIdx.x + ((j * 4 + wave) << 8);  // balanced across waves
    if (row >= n0) continue;
    const float4* fr = (const float4*)(feat + (size_t)row * FEATD);
    const float4 a0 = fr[lane * 2], a1 = fr[lane * 2 + 1];
    float sq = a0.x*a0.x + a0.y*a0.y + a0.z*a0.z + a0.w*a0.w
             + a1.x*a1.x + a1.y*a1.y + a1.z*a1.z + a1.w*a1.w;
    float acc[BATCH];
    #pragma unroll
    for (int i = 0; i < BATCH; ++i) {
      const float4 b0 = *(const float4*)(sh + i * FEATD + base);
      const float4 b1 = *(const float4*)(sh + i * FEATD + base + 4);
      acc[i] = a0.x*b0.x + a0.y*b0.y + a0.z*b0.z + a0.w*b0.w
             + a1.x*b1.x + a1.y*b1.y + a1.z*b1.z + a1.w*b1.w;
    }
    #pragma unroll
    for (int off = 32; off; off >>= 1) {
      sq += __shfl_down(sq, off);
      #pragma unroll
      for (int i = 0; i < BATCH; ++i) acc[i] += __shfl_down(acc[i], off);
    }
    if (lane == 0) {
      const float inv = 1.0f / fmaxf(sqrtf(sq), EPS_C);
      #pragma unroll
      for (int i = 0; i < BATCH; ++i) S[i * MEMN + row] = acc[i] * inv;
    }
  }
}

// Kernel 2: speculative adjacency rowsums for rows [n0, n0+16) and ||h_i||.
__global__ __launch_bounds__(256) void pre_k(
    const float* __restrict__ h_t, const float* __restrict__ adj,
    const int* __restrict__ num_nodes, float* __restrict__ pre,
    float* __restrict__ hn) {
  const int b = blockIdx.x;  // [0,16)
  const int tid = threadIdx.x;
  __shared__ float red[256];
  const int n0 = *num_nodes;
  const int row = min(n0 + b, MEMN - 1);
  const float4* r4 = (const float4*)(adj + (size_t)row * MEMN);
  float s = 0.f;
  for (int k = tid; k < MEMN / 4; k += 256) { const float4 v = r4[k]; s += v.x + v.y + v.z + v.w; }
  red[tid] = s;
  __syncthreads();
  for (int st = 128; st; st >>= 1) { if (tid < st) red[tid] += red[tid + st]; __syncthreads(); }
  if (tid == 0) pre[b] = red[0];
  __syncthreads();
  const float* h = h_t + b * FEATD;
  float sq = 0.f;
  for (int k = tid; k < FEATD; k += 256) { const float x = h[k]; sq += x * x; }
  red[tid] = sq;
  __syncthreads();
  for (int st = 128; st; st >>= 1) { if (tid < st) red[tid] += red[tid + st]; __syncthreads(); }
  if (tid == 0) hn[b] = sqrtf(red[0]);
}

// Kernel 3: the sequential 16-step scan, single block, all state in LDS.
__global__ __launch_bounds__(256) void seq_k(
    const float* __restrict__ h_t, const float* __restrict__ posin,
    const unsigned char* __restrict__ dones, const int* __restrict__ lastv,
    const float* __restrict__ feat, const float* __restrict__ posns,
    const float* __restrict__ adj, const int* __restrict__ num_nodes,
    const int* __restrict__ ptr_in, const float* __restrict__ S,
    const float* __restrict__ pre, const float* __restrict__ hnv,
    float* __restrict__ out) {
  const int tid = threadIdx.x;
  const int wave = tid >> 6, lane = tid & 63;
  __shared__ float mf[16][FEATD];  // modified-row feature side table (32 KB)
  __shared__ float mp[16][3];
  __shared__ int   midx[16];
  __shared__ float sh[FEATD];
  __shared__ float rv[256]; __shared__ int ri[256];
  __shared__ float cv[16];  __shared__ int ci[16];
  __shared__ int   edges[64][2];
  __shared__ int   s_n, s_p, s_ec, s_mc;
  __shared__ int   s_done, s_widx, s_ema, s_src, s_dst, s_fb;
  __shared__ float s_delta, s_sum;
  if (tid == 0) { s_n = *num_nodes; s_p = *ptr_in; s_ec = 0; s_mc = 0; }
  const int n0 = *num_nodes;
  __syncthreads();

  for (int step = 0; step < BATCH; ++step) {
    // stage h_step
    for (int k = tid; k < FEATD; k += 256) sh[k] = h_t[step * FEATD + k];
    __syncthreads();
    const int n_cur = s_n, mc = s_mc;

    // rescored candidates for modified rows (wave-parallel)
    for (int k = wave; k < 16; k += 4) {
      float v = -FLT_MAX; int idx = 0x7fffffff;
      if (k < mc && midx[k] < n_cur) {
        const float* fr = mf[k];
        float dot = 0.f, sq = 0.f;
        for (int e = lane; e < FEATD; e += 64) {
          const float a = fr[e], b = sh[e];
          dot += a * b; sq += a * a;
        }
        #pragma unroll
        for (int off = 32; off; off >>= 1) {
          dot += __shfl_down(dot, off);
          sq  += __shfl_down(sq, off);
        }
        if (lane == 0) { v = dot / fmaxf(sqrtf(sq), EPS_C); idx = midx[k]; }
      }
      if (lane == 0) { cv[k] = v; ci[k] = idx; }
    }

    // scan precomputed scores for unmodified original rows (coalesced)
    float bv = -FLT_MAX; int bi = 0x7fffffff;
    const float* Si = S + (size_t)step * MEMN;
    for (int j = 0; j < MEMN / 256; ++j) {
      const int r = j * 256 + tid;
      if (r >= n0) break;
      const float v = Si[r];
      bool ex = false;
      for (int m = 0; m < mc; ++m) ex |= (midx[m] == r);
      if (!ex && v > bv) { bv = v; bi = r; }  // ascending r: strict > keeps lowest idx
    }
    rv[tid] = bv; ri[tid] = bi;
    __syncthreads();
    if (tid < 16) {
      const float v = cv[tid]; const int idx = ci[tid];
      if (v > rv[tid] || (v == rv[tid] && idx < ri[tid])) { rv[tid] = v; ri[tid] = idx; }
    }
    __syncthreads();
    for (int s = 128; s; s >>= 1) {
      if (tid < s) {
        if (rv[tid + s] > rv[tid] || (rv[tid + s] == rv[tid] && ri[tid + s] < ri[tid])) {
          rv[tid] = rv[tid + s]; ri[tid] = ri[tid + s];
        }
      }
      __syncthreads();
    }

    // decision + state update (thread 0)
    if (tid == 0) {
      const int n = s_n, p = s_p;
      int best; float max_sim;
      if (n < 1) { best = 0; max_sim = -2.0f; }
      else { best = ri[0]; max_sim = rv[0] / fmaxf(hnv[step], EPS_C); }
      int bsrc = -1;
      for (int k = 0; k < s_mc; ++k) if (midx[k] == best) bsrc = k;
      float pbx, pby, pbz;
      if (bsrc >= 0) { pbx = mp[bsrc][0]; pby = mp[bsrc][1]; pbz = mp[bsrc][2]; }
      else { const float* pb = posns + (size_t)best * 3; pbx = pb[0]; pby = pb[1]; pbz = pb[2]; }
      const float dx = posin[step * 3 + 0] - pbx;
      const float dy = posin[step * 3 + 1] - pby;
      const float dz = posin[step * 3 + 2] - pbz;
      const float dist = sqrtf(dx * dx + dy * dy + dz * dz);
      const int done = dones[step] ? 1 : 0;
      const bool empty = (n < 1);
      const bool should_add = (max_sim < TAU_NEW_C) || (dist > D_MIN_C);
      const bool has_room = (n < MEMN);
      const int widx = empty ? 0 : (should_add ? (has_room ? n : p) : best);
      const bool ema = (!empty) && (!should_add);
      int srcs = -1;
      for (int k = 0; k < s_mc; ++k) if (midx[k] == widx) srcs = k;
      int dsts = srcs;
      if (!done) {
        if (srcs < 0) { dsts = s_mc; midx[dsts] = widx; s_mc = dsts + 1; }
        if (empty || (should_add && has_room)) s_n = n + 1;
        if ((!empty) && should_add && (!has_room)) s_p = (p + 1) % MEMN;
        const int last = lastv[step];
        if (last != -1 && last != widx) {
          const int lc = min(max(last, 0), MEMN - 1);
          const int ec = s_ec;
          edges[ec][0] = lc;   edges[ec][1] = widx;
          edges[ec + 1][0] = widx; edges[ec + 1][1] = lc;
          s_ec = ec + 2;
        }
      }
      s_done = done; s_widx = widx; s_ema = ema ? 1 : 0; s_src = srcs; s_dst = dsts;
      s_delta = 0.f;
      s_fb = 0;
      if (!done) {
        if (widx >= n0 && widx < n0 + BATCH) s_sum = pre[widx - n0];
        else s_fb = 1;
      }
    }
    __syncthreads();

    if (!s_done) {
      // side-table row write
      const int widx = s_widx;
      float* dstf = mf[s_dst];
      if (s_ema) {
        const float* srcf = (s_src >= 0) ? mf[s_src] : (feat + (size_t)widx * FEATD);
        for (int k = tid; k < FEATD; k += 256)
          dstf[k] = ALPHA_C * srcf[k] + (1.f - ALPHA_C) * sh[k];
      } else {
        for (int k = tid; k < FEATD; k += 256) dstf[k] = sh[k];
      }
      if (tid < 3) {
        const float sp = (s_src >= 0) ? mp[s_src][tid] : posns[(size_t)widx * 3 + tid];
        mp[s_dst][tid] = s_ema ? (ALPHA_C * sp + (1.f - ALPHA_C) * posin[step * 3 + tid])
                               : posin[step * 3 + tid];
      }
      // recorded-edge delta vs original adjacency (parallel, one global read each)
      if (tid < s_ec) {
        const int cur = widx;
        if (edges[tid][0] == cur) {
          const int c = edges[tid][1];
          bool dup = false;
          for (int e2 = 0; e2 < tid; ++e2)
            if (edges[e2][0] == cur && edges[e2][1] == c) dup = true;
          if (!dup && adj[(size_t)cur * MEMN + c] == 0.f) atomicAdd(&s_delta, 1.f);
        }
      }
    }
    __syncthreads();

    if (s_fb) {  // generic fallback rowsum (EMA/wrap path; not hit on this data)
      const float* row = adj + (size_t)s_widx * MEMN;
      float s = 0.f;
      for (int k = tid; k < MEMN; k += 256) s += row[k];
      rv[tid] = s;
      __syncthreads();
      for (int st = 128; st; st >>= 1) { if (tid < st) rv[tid] += rv[tid + st]; __syncthreads(); }
      if (tid == 0) s_sum = rv[0];
      __syncthreads();
    }
    if (tid == 0) out[step] = s_done ? 0.f : (s_sum + s_delta);
    __syncthreads();
  }
}

extern "C" void kernel_launch(void* const* d_in, const int* in_sizes, int n_in,
                              void* d_out, int out_size, void* d_ws, size_t ws_size,
                              hipStream_t stream) {
  const float*         h_t       = (const float*)d_in[0];
  const float*         cur_pos   = (const float*)d_in[1];
  const unsigned char* dones     = (const unsigned char*)d_in[2];
  const float*         node_feat = (const float*)d_in[3];
  const float*         node_pos  = (const float*)d_in[4];
  const float*         adj       = (const float*)d_in[5];
  const int*           num_nodes = (const int*)d_in[6];
  const int*           ptr_in    = (const int*)d_in[7];
  const int*           lastv     = (const int*)d_in[8];
  float* out = (float*)d_out;

  float* S   = (float*)d_ws;                  // 16*8192 floats
  float* pre = S + BATCH * MEMN;              // 16 floats
  float* hn  = pre + BATCH;                   // 16 floats

  score_k<<<256, 256, 0, stream>>>(h_t, node_feat, num_nodes, S);
  pre_k<<<BATCH, 256, 0, stream>>>(h_t, adj, num_nodes, pre, hn);
  seq_k<<<1, 256, 0, stream>>>(h_t, cur_pos, dones, lastv, node_feat, node_pos,
                               adj, num_nodes, ptr_in, S, pre, hn, out);
}

// Round 3
// 42.280 us; speedup vs baseline: 7.0481x; 5.2605x over previous
//
#include <hip/hip_runtime.h>
#include <cfloat>

#define MEMN 8192
#define FEATD 512
#define BATCH 16

static constexpr float TAU_NEW_C = 0.85f;
static constexpr float D_MIN_C  = 1.5f;
static constexpr float ALPHA_C  = 0.5f;
static constexpr float EPS_C    = 1e-8f;

// ws layout (floats unless noted):
//   pv    [16][256]  per-step per-block argmax value partials (orig rows)
//   pi    [16][256]  (int) matching row indices
//   pre   [16]       speculative adj rowsums for rows [n0, n0+16)
//   hn    [16]       ||h_i||
//   cross [16][16]   dot(h_i,h_j)/max(||h_j||,eps)
//   flag  (int)      0 = speculation valid (fast path), 1 = run fallback

// Kernel 1 (grid 273):
//   blocks 0..255  : scores of all 16 h's vs original rows + per-block argmax partials
//   blocks 256..271: speculative adjacency rowsums for rows n0+b and ||h_b||
//   block 272      : 16x16 cross-sims between h vectors
__global__ __launch_bounds__(256) void score_pre_k(
    const float* __restrict__ h_t, const float* __restrict__ feat,
    const float* __restrict__ adj, const int* __restrict__ num_nodes,
    float* __restrict__ pv, int* __restrict__ pi,
    float* __restrict__ pre, float* __restrict__ hn, float* __restrict__ cross) {
  __shared__ float sh[BATCH * FEATD];  // 32 KB
  __shared__ float red[256];
  __shared__ float sv[4][BATCH]; __shared__ int si[4][BATCH];
  const int b = blockIdx.x;
  const int tid = threadIdx.x;
  const int wave = tid >> 6, lane = tid & 63;

  if (b < 256) {
    for (int k = tid; k < BATCH * FEATD; k += 256) sh[k] = h_t[k];
    __syncthreads();
    const int n0 = *num_nodes;
    const int base = lane * 8;
    float best[BATCH]; int bidx[BATCH];
    #pragma unroll
    for (int i = 0; i < BATCH; ++i) { best[i] = -FLT_MAX; bidx[i] = 0x7fffffff; }
    for (int j = 0; j < 8; ++j) {
      const int row = b + ((j * 4 + wave) << 8);  // ascending per wave
      if (row >= n0) continue;
      const float4* fr = (const float4*)(feat + (size_t)row * FEATD);
      const float4 a0 = fr[lane * 2], a1 = fr[lane * 2 + 1];
      float sq = a0.x*a0.x + a0.y*a0.y + a0.z*a0.z + a0.w*a0.w
               + a1.x*a1.x + a1.y*a1.y + a1.z*a1.z + a1.w*a1.w;
      float acc[BATCH];
      #pragma unroll
      for (int i = 0; i < BATCH; ++i) {
        const float4 b0 = *(const float4*)(sh + i * FEATD + base);
        const float4 b1 = *(const float4*)(sh + i * FEATD + base + 4);
        acc[i] = a0.x*b0.x + a0.y*b0.y + a0.z*b0.z + a0.w*b0.w
               + a1.x*b1.x + a1.y*b1.y + a1.z*b1.z + a1.w*b1.w;
      }
      #pragma unroll
      for (int off = 32; off; off >>= 1) {
        sq += __shfl_down(sq, off);
        #pragma unroll
        for (int i = 0; i < BATCH; ++i) acc[i] += __shfl_down(acc[i], off);
      }
      if (lane == 0) {
        const float inv = 1.0f / fmaxf(sqrtf(sq), EPS_C);
        #pragma unroll
        for (int i = 0; i < BATCH; ++i) {
          const float v = acc[i] * inv;
          if (v > best[i]) { best[i] = v; bidx[i] = row; }  // strict >: lowest row wins
        }
      }
    }
    if (lane == 0) {
      #pragma unroll
      for (int i = 0; i < BATCH; ++i) { sv[wave][i] = best[i]; si[wave][i] = bidx[i]; }
    }
    __syncthreads();
    if (tid < BATCH) {
      float v = sv[0][tid]; int ix = si[0][tid];
      #pragma unroll
      for (int w = 1; w < 4; ++w)
        if (sv[w][tid] > v || (sv[w][tid] == v && si[w][tid] < ix)) { v = sv[w][tid]; ix = si[w][tid]; }
      pv[tid * 256 + b] = v; pi[tid * 256 + b] = ix;
    }
  } else if (b < 272) {
    const int bb = b - 256;
    const int n0 = *num_nodes;
    const int row = min(n0 + bb, MEMN - 1);
    const float4* r4 = (const float4*)(adj + (size_t)row * MEMN);
    float s = 0.f;
    for (int k = tid; k < MEMN / 4; k += 256) { const float4 v = r4[k]; s += v.x + v.y + v.z + v.w; }
    red[tid] = s;
    __syncthreads();
    for (int st = 128; st; st >>= 1) { if (tid < st) red[tid] += red[tid + st]; __syncthreads(); }
    if (tid == 0) pre[bb] = red[0];
    __syncthreads();
    const float* h = h_t + bb * FEATD;
    float sq = 0.f;
    for (int k = tid; k < FEATD; k += 256) { const float x = h[k]; sq += x * x; }
    red[tid] = sq;
    __syncthreads();
    for (int st = 128; st; st >>= 1) { if (tid < st) red[tid] += red[tid + st]; __syncthreads(); }
    if (tid == 0) hn[bb] = sqrtf(red[0]);
  } else {
    for (int k = tid; k < BATCH * FEATD; k += 256) sh[k] = h_t[k];
    __syncthreads();
    const int i = tid >> 4, j = tid & 15;
    float dot = 0.f, sqb = 0.f;
    for (int k = 0; k < FEATD; ++k) {
      const float a = sh[i * FEATD + k], bb2 = sh[j * FEATD + k];
      dot += a * bb2; sqb += bb2 * bb2;
    }
    cross[tid] = dot / fmaxf(sqrtf(sqb), EPS_C);
  }
}

// Kernel 2 (1 block): validate speculation; if valid, write all 16 outputs.
__global__ __launch_bounds__(256) void val_k(
    const float* __restrict__ posin, const unsigned char* __restrict__ dones,
    const int* __restrict__ lastv, const float* __restrict__ posns,
    const float* __restrict__ adj, const int* __restrict__ num_nodes,
    const float* __restrict__ pv, const int* __restrict__ pi,
    const float* __restrict__ pre, const float* __restrict__ hn,
    const float* __restrict__ cross, float* __restrict__ out,
    int* __restrict__ flag) {
  const int tid = threadIdx.x;
  const int wave = tid >> 6, lane = tid & 63;
  __shared__ float wv[BATCH][4]; __shared__ int wi[BATCH][4];
  __shared__ float s_out[BATCH];
  __shared__ int s_valid;
  float v[BATCH]; int ix[BATCH];
  #pragma unroll
  for (int s = 0; s < BATCH; ++s) { v[s] = pv[s * 256 + tid]; ix[s] = pi[s * 256 + tid]; }
  #pragma unroll
  for (int s = 0; s < BATCH; ++s) {
    float bv = v[s]; int bi = ix[s];
    #pragma unroll
    for (int off = 32; off; off >>= 1) {
      const float v2 = __shfl_down(bv, off);
      const int   i2 = __shfl_down(bi, off);
      if (v2 > bv || (v2 == bv && i2 < bi)) { bv = v2; bi = i2; }
    }
    if (lane == 0) { wv[s][wave] = bv; wi[s][wave] = bi; }
  }
  __syncthreads();
  const int n0 = *num_nodes;
  int ok = 1;
  if (tid < BATCH) {
    const int s = tid;
    float bv = wv[s][0]; int bi = wi[s][0];
    #pragma unroll
    for (int w = 1; w < 4; ++w)
      if (wv[s][w] > bv || (wv[s][w] == bv && wi[s][w] < bi)) { bv = wv[s][w]; bi = wi[s][w]; }
    for (int j = 0; j < s; ++j) {  // new rows n0+j (higher idx: strict > keeps ties on originals)
      const float cv2 = cross[s * 16 + j];
      if (cv2 > bv) { bv = cv2; bi = n0 + j; }
    }
    if (bi == 0x7fffffff) ok = 0;
    else {
      const float max_sim = bv / fmaxf(hn[s], EPS_C);
      float px, py, pz;
      if (bi >= n0) { const float* pp = posin + (size_t)(bi - n0) * 3; px = pp[0]; py = pp[1]; pz = pp[2]; }
      else          { const float* pp = posns + (size_t)bi * 3;        px = pp[0]; py = pp[1]; pz = pp[2]; }
      const float dx = posin[s * 3 + 0] - px;
      const float dy = posin[s * 3 + 1] - py;
      const float dz = posin[s * 3 + 2] - pz;
      const float dist = sqrtf(dx * dx + dy * dy + dz * dz);
      const bool should_add = (max_sim < TAU_NEW_C) || (dist > D_MIN_C);
      ok = (!dones[s]) && should_add;
      // speculative output: rowsum(n0+s) + this step's new edge if originally absent
      float o = pre[s];
      const int last = lastv[s];
      const int cur = n0 + s;
      if (last != -1 && last != cur) {
        const int lc = min(max(last, 0), MEMN - 1);
        if (adj[(size_t)cur * MEMN + lc] == 0.f) o += 1.f;
      }
      s_out[s] = o;
    }
  }
  const unsigned long long m = __ballot(tid < BATCH ? ok : 1);
  if (tid == 0) {
    const bool valid = (~m == 0ull) && (n0 >= 1) && (n0 + BATCH <= MEMN);
    *flag = valid ? 0 : 1;
    s_valid = valid ? 1 : 0;
  }
  __syncthreads();
  if (s_valid && tid < BATCH) out[tid] = s_out[tid];
}

// Kernel 3 (1 block): generic sequential fallback; early-exits when speculation held.
__global__ __launch_bounds__(256) void seq_fallback_k(
    const float* __restrict__ h_t, const float* __restrict__ posin,
    const unsigned char* __restrict__ dones, const int* __restrict__ lastv,
    const float* __restrict__ feat, const float* __restrict__ posns,
    const float* __restrict__ adj, const int* __restrict__ num_nodes,
    const int* __restrict__ ptr_in, const float* __restrict__ pre,
    const float* __restrict__ hnv, float* __restrict__ out,
    const int* __restrict__ flag) {
  if (*flag == 0) return;
  const int tid = threadIdx.x;
  const int wave = tid >> 6, lane = tid & 63;
  __shared__ float mf[16][FEATD];
  __shared__ float mp[16][3];
  __shared__ int   midx[16];
  __shared__ float sh[FEATD];
  __shared__ float rv[256]; __shared__ int ri[256];
  __shared__ int   edges[64][2];
  __shared__ int   s_n, s_p, s_ec, s_mc;
  __shared__ int   s_done, s_widx, s_ema, s_src, s_dst, s_fb;
  __shared__ float s_delta, s_sum;
  if (tid == 0) { s_n = *num_nodes; s_p = *ptr_in; s_ec = 0; s_mc = 0; }
  const int n0 = *num_nodes;
  __syncthreads();

  for (int step = 0; step < BATCH; ++step) {
    for (int k = tid; k < FEATD; k += 256) sh[k] = h_t[step * FEATD + k];
    __syncthreads();
    const int n_cur = s_n, mc = s_mc;

    // direct argmax over active rows (redirecting modified rows to the LDS side table)
    float bv = -FLT_MAX; int bi = 0x7fffffff;
    for (int r = wave; r < n_cur; r += 4) {  // ascending per wave
      const float* src = feat + (size_t)r * FEATD;
      for (int k = 0; k < 16; ++k)
        if (k < mc && midx[k] == r) src = mf[k];
      float dot = 0.f, sq2 = 0.f;
      for (int e = lane; e < FEATD; e += 64) {
        const float a = src[e], b2 = sh[e];
        dot += a * b2; sq2 += a * a;
      }
      #pragma unroll
      for (int off = 32; off; off >>= 1) {
        dot += __shfl_down(dot, off);
        sq2 += __shfl_down(sq2, off);
      }
      if (lane == 0) {
        const float vv = dot / fmaxf(sqrtf(sq2), EPS_C);
        if (vv > bv) { bv = vv; bi = r; }
      }
    }
    if (lane == 0) { rv[wave] = bv; ri[wave] = bi; }
    __syncthreads();

    if (tid == 0) {
      float fbv = rv[0]; int fbi = ri[0];
      for (int w = 1; w < 4; ++w)
        if (rv[w] > fbv || (rv[w] == fbv && ri[w] < fbi)) { fbv = rv[w]; fbi = ri[w]; }
      const int n = s_n, p = s_p;
      int best; float max_sim;
      if (n < 1) { best = 0; max_sim = -2.0f; }
      else { best = fbi; max_sim = fbv / fmaxf(hnv[step], EPS_C); }
      int bsrc = -1;
      for (int k = 0; k < s_mc; ++k) if (midx[k] == best) bsrc = k;
      float pbx, pby, pbz;
      if (bsrc >= 0) { pbx = mp[bsrc][0]; pby = mp[bsrc][1]; pbz = mp[bsrc][2]; }
      else { const float* pb = posns + (size_t)best * 3; pbx = pb[0]; pby = pb[1]; pbz = pb[2]; }
      const float dx = posin[step * 3 + 0] - pbx;
      const float dy = posin[step * 3 + 1] - pby;
      const float dz = posin[step * 3 + 2] - pbz;
      const float dist = sqrtf(dx * dx + dy * dy + dz * dz);
      const int done = dones[step] ? 1 : 0;
      const bool empty = (n < 1);
      const bool should_add = (max_sim < TAU_NEW_C) || (dist > D_MIN_C);
      const bool has_room = (n < MEMN);
      const int widx = empty ? 0 : (should_add ? (has_room ? n : p) : best);
      const bool ema = (!empty) && (!should_add);
      int srcs = -1;
      for (int k = 0; k < s_mc; ++k) if (midx[k] == widx) srcs = k;
      int dsts = srcs;
      if (!done) {
        if (srcs < 0) { dsts = s_mc; midx[dsts] = widx; s_mc = dsts + 1; }
        if (empty || (should_add && has_room)) s_n = n + 1;
        if ((!empty) && should_add && (!has_room)) s_p = (p + 1) % MEMN;
        const int last = lastv[step];
        if (last != -1 && last != widx) {
          const int lc = min(max(last, 0), MEMN - 1);
          const int ec = s_ec;
          edges[ec][0] = lc;   edges[ec][1] = widx;
          edges[ec + 1][0] = widx; edges[ec + 1][1] = lc;
          s_ec = ec + 2;
        }
      }
      s_done = done; s_widx = widx; s_ema = ema ? 1 : 0; s_src = srcs; s_dst = dsts;
      s_delta = 0.f;
      s_fb = 0;
      if (!done) {
        if (widx >= n0 && widx < n0 + BATCH) s_sum = pre[widx - n0];
        else s_fb = 1;
      }
    }
    __syncthreads();

    if (!s_done) {
      const int widx = s_widx;
      float* dstf = mf[s_dst];
      if (s_ema) {
        const float* srcf = (s_src >= 0) ? mf[s_src] : (feat + (size_t)widx * FEATD);
        for (int k = tid; k < FEATD; k += 256)
          dstf[k] = ALPHA_C * srcf[k] + (1.f - ALPHA_C) * sh[k];
      } else {
        for (int k = tid; k < FEATD; k += 256) dstf[k] = sh[k];
      }
      if (tid < 3) {
        const float sp = (s_src >= 0) ? mp[s_src][tid] : posns[(size_t)widx * 3 + tid];
        mp[s_dst][tid] = s_ema ? (ALPHA_C * sp + (1.f - ALPHA_C) * posin[step * 3 + tid])
                               : posin[step * 3 + tid];
      }
      if (tid < s_ec) {
        const int cur = widx;
        if (edges[tid][0] == cur) {
          const int c = edges[tid][1];
          bool dup = false;
          for (int e2 = 0; e2 < tid; ++e2)
            if (edges[e2][0] == cur && edges[e2][1] == c) dup = true;
          if (!dup && adj[(size_t)cur * MEMN + c] == 0.f) atomicAdd(&s_delta, 1.f);
        }
      }
    }
    __syncthreads();

    if (s_fb) {
      const float* row = adj + (size_t)s_widx * MEMN;
      float s = 0.f;
      for (int k = tid; k < MEMN; k += 256) s += row[k];
      rv[tid] = s;
      __syncthreads();
      for (int st = 128; st; st >>= 1) { if (tid < st) rv[tid] += rv[tid + st]; __syncthreads(); }
      if (tid == 0) s_sum = rv[0];
      __syncthreads();
    }
    if (tid == 0) out[step] = s_done ? 0.f : (s_sum + s_delta);
    __syncthreads();
  }
}

extern "C" void kernel_launch(void* const* d_in, const int* in_sizes, int n_in,
                              void* d_out, int out_size, void* d_ws, size_t ws_size,
                              hipStream_t stream) {
  const float*         h_t       = (const float*)d_in[0];
  const float*         cur_pos   = (const float*)d_in[1];
  const unsigned char* dones     = (const unsigned char*)d_in[2];
  const float*         node_feat = (const float*)d_in[3];
  const float*         node_pos  = (const float*)d_in[4];
  const float*         adj       = (const float*)d_in[5];
  const int*           num_nodes = (const int*)d_in[6];
  const int*           ptr_in    = (const int*)d_in[7];
  const int*           lastv     = (const int*)d_in[8];
  float* out = (float*)d_out;

  float* pv    = (float*)d_ws;              // 16*256
  int*   pi    = (int*)(pv + BATCH * 256);  // 16*256
  float* pre   = (float*)(pi + BATCH * 256);
  float* hn    = pre + BATCH;
  float* cross = hn + BATCH;                // 256
  int*   flag  = (int*)(cross + 256);

  score_pre_k<<<273, 256, 0, stream>>>(h_t, node_feat, adj, num_nodes, pv, pi, pre, hn, cross);
  val_k<<<1, 256, 0, stream>>>(cur_pos, dones, lastv, node_pos, adj, num_nodes,
                               pv, pi, pre, hn, cross, out, flag);
  seq_fallback_k<<<1, 256, 0, stream>>>(h_t, cur_pos, dones, lastv, node_feat, node_pos,
                                        adj, num_nodes, ptr_in, pre, hn, out, flag);
}

// Round 4
// 30.067 us; speedup vs baseline: 9.9108x; 1.4062x over previous
//
#include <hip/hip_runtime.h>
#include <cfloat>

#define MEMN 8192
#define FEATD 512
#define BATCH 16

static constexpr float TAU_NEW_C = 0.85f;
static constexpr float D_MIN_C  = 1.5f;
static constexpr float ALPHA_C  = 0.5f;
static constexpr float EPS_C    = 1e-8f;

// ws layout (floats unless noted):
//   pv    [16][256]  per-step per-block argmax value partials (orig rows)
//   pi    [16][256]  (int) matching row indices
//   pre   [16]       speculative adj rowsums for rows [n0, n0+16)
//   hn    [16]       ||h_i||
//   cross [16][16]   dot(h_i,h_j)/max(||h_j||,eps)

// Kernel 1 (grid 273):
//   blocks 0..255  : scores of all 16 h's vs original rows + per-block argmax partials
//   blocks 256..271: speculative adjacency rowsums for rows n0+b and ||h_b||
//   block 272      : 16x16 cross-sims, wave-parallel conflict-free layout
__global__ __launch_bounds__(256) void score_pre_k(
    const float* __restrict__ h_t, const float* __restrict__ feat,
    const float* __restrict__ adj, const int* __restrict__ num_nodes,
    float* __restrict__ pv, int* __restrict__ pi,
    float* __restrict__ pre, float* __restrict__ hn, float* __restrict__ cross) {
  __shared__ float sh[BATCH * FEATD];  // 32 KB
  __shared__ float red[256];
  __shared__ float sv[4][BATCH]; __shared__ int si[4][BATCH];
  const int b = blockIdx.x;
  const int tid = threadIdx.x;
  const int wave = tid >> 6, lane = tid & 63;

  if (b < 256) {
    for (int k = tid; k < BATCH * FEATD; k += 256) sh[k] = h_t[k];
    __syncthreads();
    const int n0 = *num_nodes;
    const int base = lane * 8;
    float best[BATCH]; int bidx[BATCH];
    #pragma unroll
    for (int i = 0; i < BATCH; ++i) { best[i] = -FLT_MAX; bidx[i] = 0x7fffffff; }
    for (int j = 0; j < 8; ++j) {
      const int row = b + ((j * 4 + wave) << 8);  // ascending per wave
      if (row >= n0) continue;
      const float4* fr = (const float4*)(feat + (size_t)row * FEATD);
      const float4 a0 = fr[lane * 2], a1 = fr[lane * 2 + 1];
      float sq = a0.x*a0.x + a0.y*a0.y + a0.z*a0.z + a0.w*a0.w
               + a1.x*a1.x + a1.y*a1.y + a1.z*a1.z + a1.w*a1.w;
      float acc[BATCH];
      #pragma unroll
      for (int i = 0; i < BATCH; ++i) {
        const float4 b0 = *(const float4*)(sh + i * FEATD + base);
        const float4 b1 = *(const float4*)(sh + i * FEATD + base + 4);
        acc[i] = a0.x*b0.x + a0.y*b0.y + a0.z*b0.z + a0.w*b0.w
               + a1.x*b1.x + a1.y*b1.y + a1.z*b1.z + a1.w*b1.w;
      }
      #pragma unroll
      for (int off = 32; off; off >>= 1) {
        sq += __shfl_down(sq, off);
        #pragma unroll
        for (int i = 0; i < BATCH; ++i) acc[i] += __shfl_down(acc[i], off);
      }
      if (lane == 0) {
        const float inv = 1.0f / fmaxf(sqrtf(sq), EPS_C);
        #pragma unroll
        for (int i = 0; i < BATCH; ++i) {
          const float v = acc[i] * inv;
          if (v > best[i]) { best[i] = v; bidx[i] = row; }  // strict >: lowest row wins
        }
      }
    }
    if (lane == 0) {
      #pragma unroll
      for (int i = 0; i < BATCH; ++i) { sv[wave][i] = best[i]; si[wave][i] = bidx[i]; }
    }
    __syncthreads();
    if (tid < BATCH) {
      float v = sv[0][tid]; int ix = si[0][tid];
      #pragma unroll
      for (int w = 1; w < 4; ++w)
        if (sv[w][tid] > v || (sv[w][tid] == v && si[w][tid] < ix)) { v = sv[w][tid]; ix = si[w][tid]; }
      pv[tid * 256 + b] = v; pi[tid * 256 + b] = ix;
    }
  } else if (b < 272) {
    const int bb = b - 256;
    const int n0 = *num_nodes;
    const int row = min(n0 + bb, MEMN - 1);
    const float4* r4 = (const float4*)(adj + (size_t)row * MEMN);
    float s = 0.f;
    for (int k = tid; k < MEMN / 4; k += 256) { const float4 v = r4[k]; s += v.x + v.y + v.z + v.w; }
    red[tid] = s;
    __syncthreads();
    for (int st = 128; st; st >>= 1) { if (tid < st) red[tid] += red[tid + st]; __syncthreads(); }
    if (tid == 0) pre[bb] = red[0];
    __syncthreads();
    const float* h = h_t + bb * FEATD;
    float sq = 0.f;
    for (int k = tid; k < FEATD; k += 256) { const float x = h[k]; sq += x * x; }
    red[tid] = sq;
    __syncthreads();
    for (int st = 128; st; st >>= 1) { if (tid < st) red[tid] += red[tid + st]; __syncthreads(); }
    if (tid == 0) hn[bb] = sqrtf(red[0]);
  } else {
    // cross-sims, wave-parallel: candidate row j (one per wave per iter), queries i=0..15.
    // cross[i*16+j] = dot(h_i, h_j) / max(||h_j||, eps)
    for (int k = tid; k < BATCH * FEATD; k += 256) sh[k] = h_t[k];
    __syncthreads();
    const int base = lane * 8;
    for (int jt = 0; jt < 4; ++jt) {
      const int j = jt * 4 + wave;
      const float4 a0 = *(const float4*)(sh + j * FEATD + base);
      const float4 a1 = *(const float4*)(sh + j * FEATD + base + 4);
      float sq = a0.x*a0.x + a0.y*a0.y + a0.z*a0.z + a0.w*a0.w
               + a1.x*a1.x + a1.y*a1.y + a1.z*a1.z + a1.w*a1.w;
      float acc[BATCH];
      #pragma unroll
      for (int i = 0; i < BATCH; ++i) {
        const float4 b0 = *(const float4*)(sh + i * FEATD + base);
        const float4 b1 = *(const float4*)(sh + i * FEATD + base + 4);
        acc[i] = a0.x*b0.x + a0.y*b0.y + a0.z*b0.z + a0.w*b0.w
               + a1.x*b1.x + a1.y*b1.y + a1.z*b1.z + a1.w*b1.w;
      }
      #pragma unroll
      for (int off = 32; off; off >>= 1) {
        sq += __shfl_down(sq, off);
        #pragma unroll
        for (int i = 0; i < BATCH; ++i) acc[i] += __shfl_down(acc[i], off);
      }
      if (lane == 0) {
        const float inv = 1.0f / fmaxf(sqrtf(sq), EPS_C);
        #pragma unroll
        for (int i = 0; i < BATCH; ++i) cross[i * 16 + j] = acc[i] * inv;
      }
    }
  }
}

// Kernel 2 (1 block): validate speculation; if valid write outputs, else run the
// generic sequential fallback in the same block.
__global__ __launch_bounds__(256) void val_fb_k(
    const float* __restrict__ h_t, const float* __restrict__ posin,
    const unsigned char* __restrict__ dones, const int* __restrict__ lastv,
    const float* __restrict__ feat, const float* __restrict__ posns,
    const float* __restrict__ adj, const int* __restrict__ num_nodes,
    const int* __restrict__ ptr_in, const float* __restrict__ pv,
    const int* __restrict__ pi, const float* __restrict__ pre,
    const float* __restrict__ hn, const float* __restrict__ cross,
    float* __restrict__ out) {
  const int tid = threadIdx.x;
  const int wave = tid >> 6, lane = tid & 63;
  __shared__ float wv[BATCH][4]; __shared__ int wi[BATCH][4];
  __shared__ float s_out[BATCH];
  __shared__ int s_valid;
  const int n0 = *num_nodes;

  // Prefetch the 16 speculative adjacency probes (overlaps reduction below).
  float adjval = 1.f;
  int lastp = -1;
  if (tid < BATCH) {
    lastp = lastv[tid];
    if (lastp != -1) {
      const int lc = min(max(lastp, 0), MEMN - 1);
      const int row = min(n0 + tid, MEMN - 1);
      adjval = adj[(size_t)row * MEMN + lc];
    }
  }

  float v[BATCH]; int ix[BATCH];
  #pragma unroll
  for (int s = 0; s < BATCH; ++s) { v[s] = pv[s * 256 + tid]; ix[s] = pi[s * 256 + tid]; }
  #pragma unroll
  for (int s = 0; s < BATCH; ++s) {
    float bv = v[s]; int bi = ix[s];
    #pragma unroll
    for (int off = 32; off; off >>= 1) {
      const float v2 = __shfl_down(bv, off);
      const int   i2 = __shfl_down(bi, off);
      if (v2 > bv || (v2 == bv && i2 < bi)) { bv = v2; bi = i2; }
    }
    if (lane == 0) { wv[s][wave] = bv; wi[s][wave] = bi; }
  }
  __syncthreads();
  int ok = 1;
  if (tid < BATCH) {
    const int s = tid;
    float bv = wv[s][0]; int bi = wi[s][0];
    #pragma unroll
    for (int w = 1; w < 4; ++w)
      if (wv[s][w] > bv || (wv[s][w] == bv && wi[s][w] < bi)) { bv = wv[s][w]; bi = wi[s][w]; }
    for (int j = 0; j < s; ++j) {  // speculative new rows n0+j (higher idx: strict >)
      const float cv2 = cross[s * 16 + j];
      if (cv2 > bv) { bv = cv2; bi = n0 + j; }
    }
    if (bi == 0x7fffffff) ok = 0;
    else {
      const float max_sim = bv / fmaxf(hn[s], EPS_C);
      float px, py, pz;
      if (bi >= n0) { const float* pp = posin + (size_t)(bi - n0) * 3; px = pp[0]; py = pp[1]; pz = pp[2]; }
      else          { const float* pp = posns + (size_t)bi * 3;        px = pp[0]; py = pp[1]; pz = pp[2]; }
      const float dx = posin[s * 3 + 0] - px;
      const float dy = posin[s * 3 + 1] - py;
      const float dz = posin[s * 3 + 2] - pz;
      const float dist = sqrtf(dx * dx + dy * dy + dz * dz);
      const bool should_add = (max_sim < TAU_NEW_C) || (dist > D_MIN_C);
      // validity also needs lastv[s] < n0 so prior edges provably never touch row n0+s
      ok = (!dones[s]) && should_add && (lastp == -1 || lastp < n0);
      float o = pre[s];
      if (lastp != -1 && lastp != n0 + s) { if (adjval == 0.f) o += 1.f; }
      s_out[s] = o;
    }
  }
  const unsigned long long m = __ballot(tid < BATCH ? ok : 1);
  if (tid == 0) s_valid = ((~m == 0ull) && (n0 >= 1) && (n0 + BATCH <= MEMN)) ? 1 : 0;
  __syncthreads();
  if (s_valid) { if (tid < BATCH) out[tid] = s_out[tid]; return; }

  // ---------------- generic sequential fallback (rare path) ----------------
  __shared__ float mf[16][FEATD];
  __shared__ float mp[16][3];
  __shared__ int   midx[16];
  __shared__ float sh[FEATD];
  __shared__ float rv[256]; __shared__ int ri[256];
  __shared__ int   edges[64][2];
  __shared__ int   s_n, s_p, s_ec, s_mc;
  __shared__ int   s_done, s_widx, s_ema, s_src, s_dst, s_fb;
  __shared__ float s_delta, s_sum;
  if (tid == 0) { s_n = n0; s_p = *ptr_in; s_ec = 0; s_mc = 0; }
  __syncthreads();

  for (int step = 0; step < BATCH; ++step) {
    for (int k = tid; k < FEATD; k += 256) sh[k] = h_t[step * FEATD + k];
    __syncthreads();
    const int n_cur = s_n, mc = s_mc;

    float bv = -FLT_MAX; int bi = 0x7fffffff;
    for (int r = wave; r < n_cur; r += 4) {  // ascending per wave
      const float* src = feat + (size_t)r * FEATD;
      for (int k = 0; k < 16; ++k)
        if (k < mc && midx[k] == r) src = mf[k];
      float dot = 0.f, sq2 = 0.f;
      for (int e = lane; e < FEATD; e += 64) {
        const float a = src[e], b2 = sh[e];
        dot += a * b2; sq2 += a * a;
      }
      #pragma unroll
      for (int off = 32; off; off >>= 1) {
        dot += __shfl_down(dot, off);
        sq2 += __shfl_down(sq2, off);
      }
      if (lane == 0) {
        const float vv = dot / fmaxf(sqrtf(sq2), EPS_C);
        if (vv > bv) { bv = vv; bi = r; }
      }
    }
    if (lane == 0) { rv[wave] = bv; ri[wave] = bi; }
    __syncthreads();

    if (tid == 0) {
      float fbv = rv[0]; int fbi = ri[0];
      for (int w = 1; w < 4; ++w)
        if (rv[w] > fbv || (rv[w] == fbv && ri[w] < fbi)) { fbv = rv[w]; fbi = ri[w]; }
      const int n = s_n, p = s_p;
      int best; float max_sim;
      if (n < 1) { best = 0; max_sim = -2.0f; }
      else { best = fbi; max_sim = fbv / fmaxf(hn[step], EPS_C); }
      int bsrc = -1;
      for (int k = 0; k < s_mc; ++k) if (midx[k] == best) bsrc = k;
      float pbx, pby, pbz;
      if (bsrc >= 0) { pbx = mp[bsrc][0]; pby = mp[bsrc][1]; pbz = mp[bsrc][2]; }
      else { const float* pb = posns + (size_t)best * 3; pbx = pb[0]; pby = pb[1]; pbz = pb[2]; }
      const float dx = posin[step * 3 + 0] - pbx;
      const float dy = posin[step * 3 + 1] - pby;
      const float dz = posin[step * 3 + 2] - pbz;
      const float dist = sqrtf(dx * dx + dy * dy + dz * dz);
      const int done = dones[step] ? 1 : 0;
      const bool empty = (n < 1);
      const bool should_add = (max_sim < TAU_NEW_C) || (dist > D_MIN_C);
      const bool has_room = (n < MEMN);
      const int widx = empty ? 0 : (should_add ? (has_room ? n : p) : best);
      const bool ema = (!empty) && (!should_add);
      int srcs = -1;
      for (int k = 0; k < s_mc; ++k) if (midx[k] == widx) srcs = k;
      int dsts = srcs;
      if (!done) {
        if (srcs < 0) { dsts = s_mc; midx[dsts] = widx; s_mc = dsts + 1; }
        if (empty || (should_add && has_room)) s_n = n + 1;
        if ((!empty) && should_add && (!has_room)) s_p = (p + 1) % MEMN;
        const int last = lastv[step];
        if (last != -1 && last != widx) {
          const int lc = min(max(last, 0), MEMN - 1);
          const int ec = s_ec;
          edges[ec][0] = lc;   edges[ec][1] = widx;
          edges[ec + 1][0] = widx; edges[ec + 1][1] = lc;
          s_ec = ec + 2;
        }
      }
      s_done = done; s_widx = widx; s_ema = ema ? 1 : 0; s_src = srcs; s_dst = dsts;
      s_delta = 0.f;
      s_fb = 0;
      if (!done) {
        if (widx >= n0 && widx < n0 + BATCH) s_sum = pre[widx - n0];
        else s_fb = 1;
      }
    }
    __syncthreads();

    if (!s_done) {
      const int widx = s_widx;
      float* dstf = mf[s_dst];
      if (s_ema) {
        const float* srcf = (s_src >= 0) ? mf[s_src] : (feat + (size_t)widx * FEATD);
        for (int k = tid; k < FEATD; k += 256)
          dstf[k] = ALPHA_C * srcf[k] + (1.f - ALPHA_C) * sh[k];
      } else {
        for (int k = tid; k < FEATD; k += 256) dstf[k] = sh[k];
      }
      if (tid < 3) {
        const float sp = (s_src >= 0) ? mp[s_src][tid] : posns[(size_t)widx * 3 + tid];
        mp[s_dst][tid] = s_ema ? (ALPHA_C * sp + (1.f - ALPHA_C) * posin[step * 3 + tid])
                               : posin[step * 3 + tid];
      }
      if (tid < s_ec) {
        const int cur = widx;
        if (edges[tid][0] == cur) {
          const int c = edges[tid][1];
          bool dup = false;
          for (int e2 = 0; e2 < tid; ++e2)
            if (edges[e2][0] == cur && edges[e2][1] == c) dup = true;
          if (!dup && adj[(size_t)cur * MEMN + c] == 0.f) atomicAdd(&s_delta, 1.f);
        }
      }
    }
    __syncthreads();

    if (s_fb) {
      const float* row = adj + (size_t)s_widx * MEMN;
      float s = 0.f;
      for (int k = tid; k < MEMN; k += 256) s += row[k];
      rv[tid] = s;
      __syncthreads();
      for (int st = 128; st; st >>= 1) { if (tid < st) rv[tid] += rv[tid + st]; __syncthreads(); }
      if (tid == 0) s_sum = rv[0];
      __syncthreads();
    }
    if (tid == 0) out[step] = s_done ? 0.f : (s_sum + s_delta);
    __syncthreads();
  }
}

extern "C" void kernel_launch(void* const* d_in, const int* in_sizes, int n_in,
                              void* d_out, int out_size, void* d_ws, size_t ws_size,
                              hipStream_t stream) {
  const float*         h_t       = (const float*)d_in[0];
  const float*         cur_pos   = (const float*)d_in[1];
  const unsigned char* dones     = (const unsigned char*)d_in[2];
  const float*         node_feat = (const float*)d_in[3];
  const float*         node_pos  = (const float*)d_in[4];
  const float*         adj       = (const float*)d_in[5];
  const int*           num_nodes = (const int*)d_in[6];
  const int*           ptr_in    = (const int*)d_in[7];
  const int*           lastv     = (const int*)d_in[8];
  float* out = (float*)d_out;

  float* pv    = (float*)d_ws;              // 16*256
  int*   pi    = (int*)(pv + BATCH * 256);  // 16*256
  float* pre   = (float*)(pi + BATCH * 256);
  float* hn    = pre + BATCH;
  float* cross = hn + BATCH;                // 256

  score_pre_k<<<273, 256, 0, stream>>>(h_t, node_feat, adj, num_nodes, pv, pi, pre, hn, cross);
  val_fb_k<<<1, 256, 0, stream>>>(h_t, cur_pos, dones, lastv, node_feat, node_pos,
                                  adj, num_nodes, ptr_in, pv, pi, pre, hn, cross, out);
}